// Round 9
// baseline (50.749 us; speedup 1.0000x reference)
//
#include <hip/hip_runtime.h>
#include <math.h>

// ---------------------------------------------------------------------------
// MyGaussianModel: bind 2M gaussians to 9976 triangle faces.
// SINGLE fused kernel: per-gaussian face-geometry recompute (faces/verts are
// 180 KB total -> L2-resident; ~200x redundancy is cache-hits + VALU slack,
// which round-8's fast-math null experiment proved is free), then transform +
// activations. Output transposed through LDS -> coalesced nt dwordx4 stores.
// Eliminates the serial face-kernel phase and its launch gap.
// ---------------------------------------------------------------------------

typedef float f32x4 __attribute__((ext_vector_type(4)));

__device__ __forceinline__ float fast_exp(float x) {
    return __builtin_amdgcn_exp2f(x * 1.4426950408889634f);   // v_exp_f32
}
__device__ __forceinline__ float fast_rcp(float x) {
    return __builtin_amdgcn_rcpf(x);                          // v_rcp_f32
}
__device__ __forceinline__ float fast_rsq(float x) {
    return __builtin_amdgcn_rsqf(x);                          // v_rsq_f32
}

struct F3 { float x, y, z; };
__device__ __forceinline__ F3 mkf3(float x, float y, float z) { F3 r; r.x = x; r.y = y; r.z = z; return r; }
__device__ __forceinline__ F3 f3sub(F3 a, F3 b) { return mkf3(a.x - b.x, a.y - b.y, a.z - b.z); }
__device__ __forceinline__ F3 f3add(F3 a, F3 b) { return mkf3(a.x + b.x, a.y + b.y, a.z + b.z); }
__device__ __forceinline__ F3 f3scl(F3 a, float s) { return mkf3(a.x * s, a.y * s, a.z * s); }
__device__ __forceinline__ float f3dot(F3 a, F3 b) { return a.x * b.x + a.y * b.y + a.z * b.z; }
__device__ __forceinline__ F3 f3cross(F3 a, F3 b) {
    return mkf3(a.y * b.z - a.z * b.y, a.z * b.x - a.x * b.z, a.x * b.y - a.y * b.x);
}

// Reference-exact face geometry (IEEE ops, same order as the JAX reference).
__device__ __forceinline__ void face_geom(const float* __restrict__ verts,
                                          const int* __restrict__ faces, int f,
                                          F3& a0, F3& a1, F3& a2, F3& ctr,
                                          float& fs, float4& quat_wxyz)
{
    int i0 = faces[3 * f + 0], i1 = faces[3 * f + 1], i2 = faces[3 * f + 2];
    F3 v0 = mkf3(verts[3 * i0], verts[3 * i0 + 1], verts[3 * i0 + 2]);
    F3 v1 = mkf3(verts[3 * i1], verts[3 * i1 + 1], verts[3 * i1 + 2]);
    F3 v2 = mkf3(verts[3 * i2], verts[3 * i2 + 1], verts[3 * i2 + 2]);

    ctr = f3scl(f3add(f3add(v0, v1), v2), (1.0f / 3.0f));

    F3 e1 = f3sub(v1, v0);
    float d1 = f3dot(e1, e1);
    float s0 = sqrtf(d1);
    a0 = f3scl(e1, 1.0f / sqrtf(fmaxf(d1, 1e-20f)));

    F3 e2 = f3sub(v2, v0);
    F3 c = f3cross(a0, e2);
    float dc = f3dot(c, c);
    a1 = f3scl(c, 1.0f / sqrtf(fmaxf(dc, 1e-20f)));

    F3 c2 = f3cross(a1, a0);
    float dc2 = f3dot(c2, c2);
    F3 n2 = f3scl(c2, 1.0f / sqrtf(fmaxf(dc2, 1e-20f)));
    a2 = mkf3(-n2.x, -n2.y, -n2.z);

    float s1 = fabsf(f3dot(c, a1));
    fs = 0.5f * (s0 + s1);

    float r00 = a0.x, r10 = a0.y, r20 = a0.z;
    float r01 = a1.x, r11 = a1.y, r21 = a1.z;
    float r02 = a2.x, r12 = a2.y, r22 = a2.z;
    float t = r00 + r11 + r22;

    float cand[4][4] = {
        { 1.0f + r00 - r11 - r22, r10 + r01,              r20 + r02,              r21 - r12 },
        { r10 + r01,              1.0f - r00 + r11 - r22, r21 + r12,              r02 - r20 },
        { r20 + r02,              r21 + r12,              1.0f - r00 - r11 + r22, r10 - r01 },
        { r21 - r12,              r02 - r20,              r10 - r01,              1.0f + t  }
    };
    float dec[4] = { r00, r11, r22, t };
    int ch = 0;
    float best = dec[0];
#pragma unroll
    for (int j = 1; j < 4; ++j) {
        if (dec[j] > best) { best = dec[j]; ch = j; }   // first-max, like jnp.argmax
    }
    float qx = cand[ch][0], qy = cand[ch][1], qz = cand[ch][2], qw = cand[ch][3];
    float inv = 1.0f / sqrtf(qx * qx + qy * qy + qz * qz + qw * qw);
    quat_wxyz = make_float4(qw * inv, qx * inv, qy * inv, qz * inv);
}

// ---------------------------------------------------------------------------
// Fused kernel: 256 gaussians/block; face geometry recomputed in-thread.
// ---------------------------------------------------------------------------
__global__ __launch_bounds__(256)
void gauss_all(const float* __restrict__ verts, const int* __restrict__ faces,
               const float* __restrict__ xyz, const float* __restrict__ opa,
               const float* __restrict__ scl, const f32x4* __restrict__ rot_raw,
               const float* __restrict__ fdc, const int* __restrict__ binding,
               float* __restrict__ out, int n)
{
    __shared__ float s_out[256 * 15];   // stride 15: gcd(15,32)=1 -> conflict-free

    int tid = threadIdx.x;
    int g0  = blockIdx.x * 256;
    int cnt = n - g0; if (cnt > 256) cnt = 256;

    if (tid < cnt) {
        int i = g0 + tid;

        // Streaming per-gaussian loads (issue early; coalesced within wave).
        float x  = xyz[3 * i + 0], y = xyz[3 * i + 1], z = xyz[3 * i + 2];
        float sc0 = scl[3 * i + 0], sc1 = scl[3 * i + 1], sc2 = scl[3 * i + 2];
        float d0 = fdc[3 * i + 0], d1 = fdc[3 * i + 1], d2 = fdc[3 * i + 2];
        float op = opa[i];
        f32x4 r  = rot_raw[i];
        int b    = binding[i];

        // Face geometry (faces/verts L2-resident; redundant but VALU-slack-free).
        F3 a0, a1, a2, ctr; float fs; float4 fq;
        face_geom(verts, faces, b, a0, a1, a2, ctr, fs, fq);

        // g = (R @ xyz) * fs + center ; R cols = a0,a1,a2
        float gx = (a0.x * x + a1.x * y + a2.x * z) * fs + ctr.x;
        float gy = (a0.y * x + a1.y * y + a2.y * z) * fs + ctr.y;
        float gz = (a0.z * x + a1.z * y + a2.z * z) * fs + ctr.z;

        float s0 = fast_exp(sc0) * fs;
        float s1 = fast_exp(sc1) * fs;
        float s2 = fast_exp(sc2) * fs;

        float o = fast_rcp(1.0f + fast_exp(-op));

        float rinv = fast_rcp(sqrtf(r.x * r.x + r.y * r.y + r.z * r.z + r.w * r.w) + 1e-12f);
        float rw = r.x * rinv, rx = r.y * rinv, ry = r.z * rinv, rz = r.w * rinv;

        // quat product (fq unit; reference's /(norm+1e-12) rounds to /1 in f32)
        float pw = fq.x, px = fq.y, py = fq.z, pz = fq.w;
        float vx = pw * rx + rw * px + (py * rz - pz * ry);
        float vy = pw * ry + rw * py + (pz * rx - px * rz);
        float vz = pw * rz + rw * pz + (px * ry - py * rx);
        float vw = pw * rw - (px * rx + py * ry + pz * rz);
        float qinv = fast_rsq(vx * vx + vy * vy + vz * vz + vw * vw);

        float c0 = fminf(fmaxf((0.5f + 0.282f * d0) * 255.0f, 0.0f), 255.0f);
        float c1 = fminf(fmaxf((0.5f + 0.282f * d1) * 255.0f, 0.0f), 255.0f);
        float c2 = fminf(fmaxf((0.5f + 0.282f * d2) * 255.0f, 0.0f), 255.0f);
        float c3 = fminf(fmaxf(o * 255.0f, 0.0f), 255.0f);

        float* po = &s_out[tid * 15];
        po[0]  = gx;        po[1]  = gy;        po[2]  = gz;
        po[3]  = s0;        po[4]  = s1;        po[5]  = s2;
        po[6]  = c0;        po[7]  = c1;        po[8]  = c2;        po[9] = c3;
        po[10] = vw * qinv; po[11] = vx * qinv; po[12] = vy * qinv; po[13] = vz * qinv;
    }
    __syncthreads();

    // fully-coalesced nontemporal dwordx4 copy-out
    int nflo = cnt * 14;
    int nfo4 = nflo >> 2;                         // 896 (cnt=256)
    f32x4* o4 = (f32x4*)(out + (size_t)g0 * 14);  // g0*56 B is 16B-aligned
    for (int j = tid; j < nfo4; j += 256) {
        int fb = 4 * j;
        int q  = fb / 14;
        int rr = fb - q * 14;             // 0..13
        int base = q * 15 + rr;
        f32x4 v;
        v.x = s_out[base];
        v.y = s_out[base + 1 + (rr >= 13 ? 1 : 0)];
        v.z = s_out[base + 2 + (rr >= 12 ? 1 : 0)];
        v.w = s_out[base + 3 + (rr >= 11 ? 1 : 0)];
        __builtin_nontemporal_store(v, o4 + j);
    }
    for (int f = (nfo4 << 2) + tid; f < nflo; f += 256) {
        __builtin_nontemporal_store(s_out[(f / 14) * 15 + f % 14],
                                    out + (size_t)g0 * 14 + f);
    }
}

extern "C" void kernel_launch(void* const* d_in, const int* in_sizes, int n_in,
                              void* d_out, int out_size, void* d_ws, size_t ws_size,
                              hipStream_t stream)
{
    const float* verts   = (const float*)d_in[0];
    const float* xyz     = (const float*)d_in[1];
    const float* opa     = (const float*)d_in[2];
    const float* scl     = (const float*)d_in[3];
    const float* rot     = (const float*)d_in[4];
    const float* fdc     = (const float*)d_in[5];
    // d_in[6] = features_rest : unused by the reference output — never read.
    const int*   faces   = (const int*)d_in[7];
    const int*   binding = (const int*)d_in[8];

    int n = in_sizes[8];   // N_GAUSS
    float* out = (float*)d_out;

    hipLaunchKernelGGL(gauss_all, dim3((n + 255) / 256), dim3(256), 0, stream,
                       verts, faces, xyz, opa, scl, (const f32x4*)rot, fdc, binding, out, n);
}

// Round 10
// 43.446 us; speedup vs baseline: 1.1681x; 1.1681x over previous
//
#include <hip/hip_runtime.h>
#include <math.h>

// ---------------------------------------------------------------------------
// MyGaussianModel: bind 2M gaussians to 9976 triangle faces.
// Phase 1: per-face quat+center+scale -> 32 B/face table in d_ws (319 KB,
//          L2-resident). 64-thread blocks.
// Phase 2: per-gaussian: gather 2 float4/face (L2), reconstruct R from quat,
//          transform + activations. Inputs: plain temporal loads (compiler
//          merges stride-12 components into dwordx3; adjacent lanes share
//          lines). Transcendentals via fast HW ops (v_exp/v_rcp/v_rsq).
//          Output transposed through LDS, nontemporal coalesced dwordx4
//          stores. Measured optimum (round 8: 43.6 us, ~85% of the measured
//          6.29 TB/s copy ceiling on 232 MB of mandatory traffic).
// Rejected by experiment: 4-gauss/thread private arrays (R2: +43 us),
// nontemporal scalar loads (R5: +10 us), full fusion of face recompute
// (R9: +7 us, serial gather chain), input LDS staging (R4 vs R3: slower).
// ---------------------------------------------------------------------------

typedef float f32x4 __attribute__((ext_vector_type(4)));

__device__ __forceinline__ float fast_exp(float x) {
    return __builtin_amdgcn_exp2f(x * 1.4426950408889634f);   // v_exp_f32
}
__device__ __forceinline__ float fast_rcp(float x) {
    return __builtin_amdgcn_rcpf(x);                          // v_rcp_f32
}
__device__ __forceinline__ float fast_rsq(float x) {
    return __builtin_amdgcn_rsqf(x);                          // v_rsq_f32
}

struct F3 { float x, y, z; };
__device__ __forceinline__ F3 mkf3(float x, float y, float z) { F3 r; r.x = x; r.y = y; r.z = z; return r; }
__device__ __forceinline__ F3 f3sub(F3 a, F3 b) { return mkf3(a.x - b.x, a.y - b.y, a.z - b.z); }
__device__ __forceinline__ F3 f3add(F3 a, F3 b) { return mkf3(a.x + b.x, a.y + b.y, a.z + b.z); }
__device__ __forceinline__ F3 f3scl(F3 a, float s) { return mkf3(a.x * s, a.y * s, a.z * s); }
__device__ __forceinline__ float f3dot(F3 a, F3 b) { return a.x * b.x + a.y * b.y + a.z * b.z; }
__device__ __forceinline__ F3 f3cross(F3 a, F3 b) {
    return mkf3(a.y * b.z - a.z * b.y, a.z * b.x - a.x * b.z, a.x * b.y - a.y * b.x);
}

__device__ void face_geom(const float* __restrict__ verts, const int* __restrict__ faces, int f,
                          F3& a0, F3& a1, F3& a2, F3& ctr, float& fs, float4& quat_wxyz)
{
    int i0 = faces[3 * f + 0], i1 = faces[3 * f + 1], i2 = faces[3 * f + 2];
    F3 v0 = mkf3(verts[3 * i0], verts[3 * i0 + 1], verts[3 * i0 + 2]);
    F3 v1 = mkf3(verts[3 * i1], verts[3 * i1 + 1], verts[3 * i1 + 2]);
    F3 v2 = mkf3(verts[3 * i2], verts[3 * i2 + 1], verts[3 * i2 + 2]);

    ctr = f3scl(f3add(f3add(v0, v1), v2), (1.0f / 3.0f));

    F3 e1 = f3sub(v1, v0);
    float d1 = f3dot(e1, e1);
    float s0 = sqrtf(d1);
    a0 = f3scl(e1, 1.0f / sqrtf(fmaxf(d1, 1e-20f)));

    F3 e2 = f3sub(v2, v0);
    F3 c = f3cross(a0, e2);
    float dc = f3dot(c, c);
    a1 = f3scl(c, 1.0f / sqrtf(fmaxf(dc, 1e-20f)));

    F3 c2 = f3cross(a1, a0);
    float dc2 = f3dot(c2, c2);
    F3 n2 = f3scl(c2, 1.0f / sqrtf(fmaxf(dc2, 1e-20f)));
    a2 = mkf3(-n2.x, -n2.y, -n2.z);

    float s1 = fabsf(f3dot(c, a1));
    fs = 0.5f * (s0 + s1);

    float r00 = a0.x, r10 = a0.y, r20 = a0.z;
    float r01 = a1.x, r11 = a1.y, r21 = a1.z;
    float r02 = a2.x, r12 = a2.y, r22 = a2.z;
    float t = r00 + r11 + r22;

    float cand[4][4] = {
        { 1.0f + r00 - r11 - r22, r10 + r01,              r20 + r02,              r21 - r12 },
        { r10 + r01,              1.0f - r00 + r11 - r22, r21 + r12,              r02 - r20 },
        { r20 + r02,              r21 + r12,              1.0f - r00 - r11 + r22, r10 - r01 },
        { r21 - r12,              r02 - r20,              r10 - r01,              1.0f + t  }
    };
    float dec[4] = { r00, r11, r22, t };
    int ch = 0;
    float best = dec[0];
#pragma unroll
    for (int j = 1; j < 4; ++j) {
        if (dec[j] > best) { best = dec[j]; ch = j; }
    }
    float qx = cand[ch][0], qy = cand[ch][1], qz = cand[ch][2], qw = cand[ch][3];
    float inv = 1.0f / sqrtf(qx * qx + qy * qy + qz * qz + qw * qw);
    quat_wxyz = make_float4(qw * inv, qx * inv, qy * inv, qz * inv);
}

// Compact table: fd[2f] = quat (w,x,y,z); fd[2f+1] = (cx,cy,cz,fs)
__global__ __launch_bounds__(64)
void face_kernel2(const float* __restrict__ verts, const int* __restrict__ faces,
                  f32x4* __restrict__ fd, int nf)
{
    int f = blockIdx.x * 64 + threadIdx.x;
    if (f >= nf) return;
    F3 a0, a1, a2, ctr; float fs; float4 quat;
    face_geom(verts, faces, f, a0, a1, a2, ctr, fs, quat);
    f32x4 q; q.x = quat.x; q.y = quat.y; q.z = quat.z; q.w = quat.w;
    f32x4 c; c.x = ctr.x;  c.y = ctr.y;  c.z = ctr.z;  c.w = fs;
    fd[2 * f + 0] = q;
    fd[2 * f + 1] = c;
}

// ---------------------------------------------------------------------------
// Main kernel: 256 gaussians/block. Plain coalesced input loads, temporal
// face-table gather, R from quat, fast transcendentals, LDS output
// transpose, nt dwordx4 stores.
// ---------------------------------------------------------------------------
__global__ __launch_bounds__(256)
void gauss_q(const float* __restrict__ xyz, const float* __restrict__ opa,
             const float* __restrict__ scl, const f32x4* __restrict__ rot_raw,
             const float* __restrict__ fdc, const int* __restrict__ binding,
             const f32x4* __restrict__ face, float* __restrict__ out, int n)
{
    __shared__ float s_out[256 * 15];   // stride 15: gcd(15,32)=1 -> conflict-free

    int tid = threadIdx.x;
    int g0  = blockIdx.x * 256;
    int cnt = n - g0; if (cnt > 256) cnt = 256;

    if (tid < cnt) {
        int i = g0 + tid;
        int b = binding[i];                       // coalesced dword
        f32x4 q4 = face[2 * b + 0];               // L2-resident gather (temporal)
        f32x4 cf = face[2 * b + 1];
        float qw = q4.x, qx = q4.y, qy = q4.z, qz = q4.w;
        float fs = cf.w;

        // R from unit quat (matches reference Shepperd inverse to ~1e-7)
        float xx = qx * qx, yy = qy * qy, zz = qz * qz;
        float xy = qx * qy, xz = qx * qz, yz = qy * qz;
        float wx = qw * qx, wy = qw * qy, wz = qw * qz;
        float r00 = 1.0f - 2.0f * (yy + zz), r01 = 2.0f * (xy - wz), r02 = 2.0f * (xz + wy);
        float r10 = 2.0f * (xy + wz), r11 = 1.0f - 2.0f * (xx + zz), r12 = 2.0f * (yz - wx);
        float r20 = 2.0f * (xz - wy), r21 = 2.0f * (yz + wx), r22 = 1.0f - 2.0f * (xx + yy);

        float x = xyz[3 * i + 0], y = xyz[3 * i + 1], z = xyz[3 * i + 2];
        float gx = (r00 * x + r01 * y + r02 * z) * fs + cf.x;
        float gy = (r10 * x + r11 * y + r12 * z) * fs + cf.y;
        float gz = (r20 * x + r21 * y + r22 * z) * fs + cf.z;

        float s0 = fast_exp(scl[3 * i + 0]) * fs;
        float s1 = fast_exp(scl[3 * i + 1]) * fs;
        float s2 = fast_exp(scl[3 * i + 2]) * fs;

        float o = fast_rcp(1.0f + fast_exp(-opa[i]));

        f32x4 r = rot_raw[i];
        float rinv = fast_rcp(sqrtf(r.x * r.x + r.y * r.y + r.z * r.z + r.w * r.w) + 1e-12f);
        float rw = r.x * rinv, rx = r.y * rinv, ry = r.z * rinv, rz = r.w * rinv;

        // quat product (fq is unit; reference's /(norm+1e-12) rounds to /1 in f32)
        float vx = qw * rx + rw * qx + (qy * rz - qz * ry);
        float vy = qw * ry + rw * qy + (qz * rx - qx * rz);
        float vz = qw * rz + rw * qz + (qx * ry - qy * rx);
        float vw = qw * rw - (qx * rx + qy * ry + qz * rz);
        float qinv = fast_rsq(vx * vx + vy * vy + vz * vz + vw * vw);

        float d0 = fdc[3 * i + 0], d1 = fdc[3 * i + 1], d2 = fdc[3 * i + 2];
        float c0 = fminf(fmaxf((0.5f + 0.282f * d0) * 255.0f, 0.0f), 255.0f);
        float c1 = fminf(fmaxf((0.5f + 0.282f * d1) * 255.0f, 0.0f), 255.0f);
        float c2 = fminf(fmaxf((0.5f + 0.282f * d2) * 255.0f, 0.0f), 255.0f);
        float c3 = fminf(fmaxf(o * 255.0f, 0.0f), 255.0f);

        float* po = &s_out[tid * 15];
        po[0]  = gx;        po[1]  = gy;        po[2]  = gz;
        po[3]  = s0;        po[4]  = s1;        po[5]  = s2;
        po[6]  = c0;        po[7]  = c1;        po[8]  = c2;        po[9] = c3;
        po[10] = vw * qinv; po[11] = vx * qinv; po[12] = vy * qinv; po[13] = vz * qinv;
    }
    __syncthreads();

    // fully-coalesced nontemporal dwordx4 copy-out.
    int nflo = cnt * 14;
    int nfo4 = nflo >> 2;                         // 896 (cnt=256)
    f32x4* o4 = (f32x4*)(out + (size_t)g0 * 14);  // g0*56 B is 16B-aligned
    for (int j = tid; j < nfo4; j += 256) {
        int fb = 4 * j;
        int q  = fb / 14;
        int rr = fb - q * 14;             // 0..13
        int base = q * 15 + rr;
        f32x4 v;
        v.x = s_out[base];
        v.y = s_out[base + 1 + (rr >= 13 ? 1 : 0)];
        v.z = s_out[base + 2 + (rr >= 12 ? 1 : 0)];
        v.w = s_out[base + 3 + (rr >= 11 ? 1 : 0)];
        __builtin_nontemporal_store(v, o4 + j);
    }
    for (int f = (nfo4 << 2) + tid; f < nflo; f += 256) {
        __builtin_nontemporal_store(s_out[(f / 14) * 15 + f % 14],
                                    out + (size_t)g0 * 14 + f);
    }
}

// Fallback if ws_size is too small for the face table (not expected).
__global__ __launch_bounds__(256)
void gauss_fused(const float* __restrict__ verts, const int* __restrict__ faces,
                 const float* __restrict__ xyz, const float* __restrict__ opa,
                 const float* __restrict__ scl, const f32x4* __restrict__ rot_raw,
                 const float* __restrict__ fdc, const int* __restrict__ binding,
                 float* __restrict__ out, int n)
{
    int i = blockIdx.x * 256 + threadIdx.x;
    if (i >= n) return;
    int b = binding[i];
    F3 a0, a1, a2, ctr; float fs; float4 quat;
    face_geom(verts, faces, b, a0, a1, a2, ctr, fs, quat);

    float x = xyz[3 * i], y = xyz[3 * i + 1], z = xyz[3 * i + 2];
    float gx = (a0.x * x + a1.x * y + a2.x * z) * fs + ctr.x;
    float gy = (a0.y * x + a1.y * y + a2.y * z) * fs + ctr.y;
    float gz = (a0.z * x + a1.z * y + a2.z * z) * fs + ctr.z;
    float s0 = expf(scl[3 * i + 0]) * fs;
    float s1 = expf(scl[3 * i + 1]) * fs;
    float s2 = expf(scl[3 * i + 2]) * fs;
    float o = 1.0f / (1.0f + expf(-opa[i]));
    f32x4 r = rot_raw[i];
    float rinv = 1.0f / (sqrtf(r.x * r.x + r.y * r.y + r.z * r.z + r.w * r.w) + 1e-12f);
    float rw = r.x * rinv, rx = r.y * rinv, ry = r.z * rinv, rz = r.w * rinv;
    float pw = quat.x, px = quat.y, py = quat.z, pz = quat.w;
    float vx = pw * rx + rw * px + (py * rz - pz * ry);
    float vy = pw * ry + rw * py + (pz * rx - px * rz);
    float vz = pw * rz + rw * pz + (px * ry - py * rx);
    float vw = pw * rw - (px * rx + py * ry + pz * rz);
    float qinv = 1.0f / sqrtf(vx * vx + vy * vy + vz * vz + vw * vw);
    float* po = out + (size_t)i * 14;
    po[0] = gx; po[1] = gy; po[2] = gz;
    po[3] = s0; po[4] = s1; po[5] = s2;
    po[6] = fminf(fmaxf((0.5f + 0.282f * fdc[3 * i + 0]) * 255.0f, 0.0f), 255.0f);
    po[7] = fminf(fmaxf((0.5f + 0.282f * fdc[3 * i + 1]) * 255.0f, 0.0f), 255.0f);
    po[8] = fminf(fmaxf((0.5f + 0.282f * fdc[3 * i + 2]) * 255.0f, 0.0f), 255.0f);
    po[9] = fminf(fmaxf(o * 255.0f, 0.0f), 255.0f);
    po[10] = vw * qinv; po[11] = vx * qinv; po[12] = vy * qinv; po[13] = vz * qinv;
}

extern "C" void kernel_launch(void* const* d_in, const int* in_sizes, int n_in,
                              void* d_out, int out_size, void* d_ws, size_t ws_size,
                              hipStream_t stream)
{
    const float* verts   = (const float*)d_in[0];
    const float* xyz     = (const float*)d_in[1];
    const float* opa     = (const float*)d_in[2];
    const float* scl     = (const float*)d_in[3];
    const float* rot     = (const float*)d_in[4];
    const float* fdc     = (const float*)d_in[5];
    // d_in[6] = features_rest : unused by the reference output — never read.
    const int*   faces   = (const int*)d_in[7];
    const int*   binding = (const int*)d_in[8];

    int n      = in_sizes[8];        // N_GAUSS
    int nfaces = in_sizes[7] / 3;    // N_FACES
    float* out = (float*)d_out;

    size_t need = (size_t)nfaces * 2 * sizeof(f32x4);

    if (ws_size >= need) {
        f32x4* face = (f32x4*)d_ws;
        hipLaunchKernelGGL(face_kernel2, dim3((nfaces + 63) / 64), dim3(64), 0, stream,
                           verts, faces, face, nfaces);
        hipLaunchKernelGGL(gauss_q, dim3((n + 255) / 256), dim3(256), 0, stream,
                           xyz, opa, scl, (const f32x4*)rot, fdc, binding, face, out, n);
    } else {
        hipLaunchKernelGGL(gauss_fused, dim3((n + 255) / 256), dim3(256), 0, stream,
                           verts, faces, xyz, opa, scl, (const f32x4*)rot, fdc, binding, out, n);
    }
}